// Round 18
// baseline (238.899 us; speedup 1.0000x reference)
//
#include <hip/hip_runtime.h>

// Problem constants
#define Hn  16
#define Dh  64
#define Bb  4
#define Tn  2048
#define En  1024
#define Mn  8192           // B*T
#define N1  3072           // 3*E
#define Kn  1024           // E

typedef __attribute__((ext_vector_type(8)))  short  short8;
typedef __attribute__((ext_vector_type(4)))  short  short4v;
typedef __attribute__((ext_vector_type(4)))  float  f32x4;
typedef __attribute__((ext_vector_type(16))) float  f32x16;
typedef __attribute__((ext_vector_type(8)))  __bf16 bf16x8;
typedef __attribute__((ext_vector_type(4)))  int    i32x4;

__device__ __forceinline__ float b2f(short s) {
  unsigned u = ((unsigned)(unsigned short)s) << 16;
  return __builtin_bit_cast(float, u);
}
__device__ __forceinline__ short f2b(float f) {
  unsigned u = __builtin_bit_cast(unsigned, f);
  u += 0x7fffu + ((u >> 16) & 1u);
  return (short)(u >> 16);
}
__device__ __forceinline__ f32x4 mfma16(short8 a, short8 b, f32x4 c) {
  return __builtin_amdgcn_mfma_f32_16x16x32_bf16(
      __builtin_bit_cast(bf16x8, a), __builtin_bit_cast(bf16x8, b), c, 0, 0, 0);
}
__device__ __forceinline__ f32x16 mfma32(short8 a, short8 b, f32x16 c) {
  return __builtin_amdgcn_mfma_f32_32x32x16_bf16(
      __builtin_bit_cast(bf16x8, a), __builtin_bit_cast(bf16x8, b), c, 0, 0, 0);
}
__device__ __forceinline__ void gload16(const void* g, void* l) {
  __builtin_amdgcn_global_load_lds(
      (const __attribute__((address_space(1))) unsigned int*)g,
      (__attribute__((address_space(3))) unsigned int*)l, 16, 0, 0);
}
// pack two f32 into (hi16(b)<<16 | hi16(a)) with one v_perm_b32
__device__ __forceinline__ unsigned packtrunc(float a, float b) {
  return __builtin_amdgcn_perm(__builtin_bit_cast(unsigned, b),
                               __builtin_bit_cast(unsigned, a), 0x07060302u);
}
// max tree as nested triples -> v_max3_f32 fusion; bit-exact (max associative)
__device__ __forceinline__ float vmax16(f32x16 v) {
  float a0 = fmaxf(fmaxf(v[0],  v[1]),  v[2]);
  float a1 = fmaxf(fmaxf(v[3],  v[4]),  v[5]);
  float a2 = fmaxf(fmaxf(v[6],  v[7]),  v[8]);
  float a3 = fmaxf(fmaxf(v[9],  v[10]), v[11]);
  float a4 = fmaxf(fmaxf(v[12], v[13]), v[14]);
  float b0 = fmaxf(fmaxf(a0, a1), a2);
  float b1 = fmaxf(fmaxf(a3, a4), v[15]);
  return fmaxf(b0, b1);
}
__device__ __forceinline__ float vsum16(f32x16 v) {
  float a0 = v[0]+v[1], a1 = v[2]+v[3], a2 = v[4]+v[5], a3 = v[6]+v[7];
  float a4 = v[8]+v[9], a5 = v[10]+v[11], a6 = v[12]+v[13], a7 = v[14]+v[15];
  return ((a0+a1)+(a2+a3)) + ((a4+a5)+(a6+a7));
}

// ---------------- merged preprocessing: cvt_x + transpose both W ----------------
__global__ __launch_bounds__(256) void prep_kernel(
    const float* __restrict__ x, short* __restrict__ xb,
    const float* __restrict__ Wqkv, short* __restrict__ wqkvT,
    const float* __restrict__ Wproj, short* __restrict__ wprojT) {
  __shared__ float tile[32][33];
  const int bid = blockIdx.x, tid = threadIdx.x;
  if (bid < 4096) {
    const size_t i = ((size_t)bid * 256 + tid) * 8;
    f32x4 a = *(const f32x4*)&x[i];
    f32x4 b = *(const f32x4*)&x[i + 4];
    short8 o;
    o[0]=f2b(a[0]); o[1]=f2b(a[1]); o[2]=f2b(a[2]); o[3]=f2b(a[3]);
    o[4]=f2b(b[0]); o[5]=f2b(b[1]); o[6]=f2b(b[2]); o[7]=f2b(b[3]);
    *(short8*)&xb[i] = o;
    return;
  }
  const float* in; short* out; int R, C, bx, by;
  if (bid < 4096 + 3072) {
    const int b2 = bid - 4096;
    in = Wqkv; out = wqkvT; R = Kn; C = N1; bx = b2 % 96; by = b2 / 96;
  } else {
    const int b3 = bid - 7168;
    in = Wproj; out = wprojT; R = Kn; C = En; bx = b3 % 32; by = b3 / 32;
  }
  const int c0 = bx * 32, r0 = by * 32;
  const int lr = tid >> 3, lc = (tid & 7) * 4;
  f32x4 v = *(const f32x4*)&in[(size_t)(r0 + lr) * C + c0 + lc];
  tile[lr][lc] = v[0]; tile[lr][lc+1] = v[1]; tile[lr][lc+2] = v[2]; tile[lr][lc+3] = v[3];
  __syncthreads();
  const int oc = tid >> 3, orr = (tid & 7) * 4;
  short4v ov;
  ov[0] = f2b(tile[orr][oc]);   ov[1] = f2b(tile[orr+1][oc]);
  ov[2] = f2b(tile[orr+2][oc]); ov[3] = f2b(tile[orr+3][oc]);
  *(short4v*)&out[(size_t)(c0 + oc) * R + r0 + orr] = ov;
}

// ---------------- GEMM1 (round-13 proven: fused LN + coalesced epilogue) ----------------
__global__ __launch_bounds__(256) void gemm1_kernel(
    const short* __restrict__ A, const short* __restrict__ Bt,
    const float* __restrict__ bias,
    short* __restrict__ qo, short* __restrict__ ko2, short* __restrict__ vo,
    const float* __restrict__ qg, const float* __restrict__ qb,
    const float* __restrict__ kg, const float* __restrict__ kb,
    int NBX, int cpx) {
  __shared__ short S[8192];
  const int lin = blockIdx.x;
  const int swz = (lin & 7) * cpx + (lin >> 3);
  const int bx = swz % NBX, by = swz / NBX;
  const int tid = threadIdx.x, lane = tid & 63, w = tid >> 6;
  const int rowBase = by * 128, colBase = bx * 128;
  f32x4 acc[4][4] = {};
  const int srow = tid >> 2, sk = (tid & 3) << 3;
  const short* Ag = A  + (size_t)(rowBase + srow) * Kn + sk;
  const short* Bg = Bt + (size_t)(colBase + srow) * Kn + sk;
  short* AsW = S + w * 512;
  short* BsW = S + 4096 + w * 512;
  const int ar = (w >> 1) * 64, bc = (w & 1) * 64;
  const int lg = lane >> 4, lg8 = lg * 8, lr = lane & 15;

  for (int kt = 0; kt < Kn; kt += 32) {
    __syncthreads();
    gload16(Ag + kt,            AsW);
    gload16(Ag + kt + 64 * Kn,  AsW + 2048);
    gload16(Bg + kt,            BsW);
    gload16(Bg + kt + 64 * Kn,  BsW + 2048);
    __syncthreads();
    short8 af[4], bfr[4];
#pragma unroll
    for (int m = 0; m < 4; ++m) af[m]  = *(const short8*)&S[(ar + m*16 + lr)*32 + lg8];
#pragma unroll
    for (int n = 0; n < 4; ++n) bfr[n] = *(const short8*)&S[4096 + (bc + n*16 + lr)*32 + lg8];
#pragma unroll
    for (int m = 0; m < 4; ++m)
#pragma unroll
      for (int n = 0; n < 4; ++n)
        acc[m][n] = mfma16(af[m], bfr[n], acc[m][n]);
  }

  const int gr0 = rowBase + ar + lg * 4;
  const int gc0 = colBase + bc + lr;

  float bb[4];
#pragma unroll
  for (int n = 0; n < 4; ++n) bb[n] = bias[gc0 + n * 16];
#pragma unroll
  for (int m = 0; m < 4; ++m)
#pragma unroll
    for (int n = 0; n < 4; ++n)
#pragma unroll
      for (int r = 0; r < 4; ++r) acc[m][n][r] += bb[n];

  const int which = colBase >> 10;            // block-uniform: 0=q 1=k 2=v
  if (which < 2) {
    const float* gp = (which == 0) ? qg : kg;
    const float* bp = (which == 0) ? qb : kb;
    const float sc = (which == 0) ? 0.1803368801111204f : 1.0f;  // 0.125*log2(e)
    float gam[4], bet[4];
#pragma unroll
    for (int n = 0; n < 4; ++n) { gam[n] = gp[n * 16 + lr]; bet[n] = bp[n * 16 + lr]; }
#pragma unroll
    for (int m = 0; m < 4; ++m)
#pragma unroll
      for (int r = 0; r < 4; ++r) {
        float s1 = 0.f, s2 = 0.f;
#pragma unroll
        for (int n = 0; n < 4; ++n) {
          const float v = acc[m][n][r];
          s1 += v; s2 += v * v;
        }
#pragma unroll
        for (int off = 1; off < 16; off <<= 1) {
          s1 += __shfl_xor(s1, off);
          s2 += __shfl_xor(s2, off);
        }
        const float mu = s1 * 0.015625f;
        const float rs = rsqrtf(s2 * 0.015625f - mu * mu + 1e-5f);
#pragma unroll
        for (int n = 0; n < 4; ++n)
          acc[m][n][r] = ((acc[m][n][r] - mu) * rs * gam[n] + bet[n]) * sc;
      }
  }

  __syncthreads();
  short* Sw = S + w * 2048;
  const int t0 = (rowBase & 2047) + ar;
  const int bidx = (rowBase + ar) >> 11;
  const int hh = ((colBase + bc) & 1023) >> 6;
  const int bh = bidx * Hn + hh;
  const int l8 = lane & 7, ld8 = lane >> 3;

  if (which < 2) {
    short* dst0 = (which == 0) ? qo : ko2;
#pragma unroll
    for (int p = 0; p < 2; ++p) {
#pragma unroll
      for (int mm = 0; mm < 2; ++mm) {
        const int m = p * 2 + mm;
#pragma unroll
        for (int n = 0; n < 4; ++n)
#pragma unroll
          for (int r = 0; r < 4; ++r) {
            const int tl = mm*16 + lg*4 + r;
            const int dl = n*16 + lr;
            Sw[tl*64 + (dl ^ ((tl & 7) << 3))] = f2b(acc[m][n][r]);
          }
      }
#pragma unroll
      for (int i = 0; i < 4; ++i) {
        const int tl = i*8 + ld8;
        short8 v = *(const short8*)&Sw[tl*64 + ((l8*8) ^ ((tl & 7) << 3))];
        const int t = t0 + p*32 + tl;
        *(short8*)&dst0[((size_t)bh * Tn + t) * Dh + l8*8] = v;
      }
    }
  } else {
#pragma unroll
    for (int p = 0; p < 2; ++p) {
#pragma unroll
      for (int nn = 0; nn < 2; ++nn) {
        const int n = p * 2 + nn;
#pragma unroll
        for (int m = 0; m < 4; ++m)
#pragma unroll
          for (int r = 0; r < 4; ++r) {
            const int dl = nn*16 + lr;
            const int tc = m*16 + lg*4 + r;
            Sw[dl*64 + (tc ^ ((dl & 7) << 3))] = f2b(acc[m][n][r]);
          }
      }
#pragma unroll
      for (int i = 0; i < 4; ++i) {
        const int dl = i*8 + ld8;
        short8 v = *(const short8*)&Sw[dl*64 + ((l8*8) ^ ((dl & 7) << 3))];
        const int d = p*32 + dl;
        *(short8*)&vo[((size_t)bh * Dh + d) * Tn + t0 + l8*8] = v;
      }
    }
  }
}

// ---------------- GEMM2: 64x128 tiles (round-17 proven) ----------------
__global__ __launch_bounds__(256) void gemm2_kernel(
    const short* __restrict__ A, const short* __restrict__ Bt,
    const float* __restrict__ bias, float* __restrict__ Cf,
    int N, int NBX, int cpx) {
  __shared__ short S[6144];     // A 64x32 (2048 sh) | B 128x32 (4096 sh)
  const int lin = blockIdx.x;
  const int swz = (lin & 7) * cpx + (lin >> 3);
  const int bx = swz % NBX, by = swz / NBX;
  const int tid = threadIdx.x, lane = tid & 63, w = tid >> 6;
  const int rowBase = by * 64, colBase = bx * 128;
  f32x4 acc[2][4] = {};
  const int srow = tid >> 2, sk = (tid & 3) << 3;
  const short* Ag = A  + (size_t)(rowBase + srow) * Kn + sk;
  const short* Bg = Bt + (size_t)(colBase + srow) * Kn + sk;
  const int ar = (w >> 1) * 32, bc = (w & 1) * 64;
  const int lg = lane >> 4, lg8 = lg * 8, lr = lane & 15;

  for (int kt = 0; kt < Kn; kt += 32) {
    __syncthreads();
    gload16(Ag + kt,            S + w * 512);          // A rows 0..63
    gload16(Bg + kt,            S + 2048 + w * 512);   // B rows 0..63
    gload16(Bg + kt + 64 * Kn,  S + 4096 + w * 512);   // B rows 64..127
    __syncthreads();
    short8 af[2], bfr[4];
#pragma unroll
    for (int m = 0; m < 2; ++m) af[m]  = *(const short8*)&S[(ar + m*16 + lr)*32 + lg8];
#pragma unroll
    for (int n = 0; n < 4; ++n) bfr[n] = *(const short8*)&S[2048 + (bc + n*16 + lr)*32 + lg8];
#pragma unroll
    for (int m = 0; m < 2; ++m)
#pragma unroll
      for (int n = 0; n < 4; ++n)
        acc[m][n] = mfma16(af[m], bfr[n], acc[m][n]);
  }

  const int gr0 = rowBase + ar + lg * 4;
  const int gc0 = colBase + bc + lr;
  float bb[4];
#pragma unroll
  for (int n = 0; n < 4; ++n) bb[n] = bias[gc0 + n * 16];
#pragma unroll
  for (int m = 0; m < 2; ++m)
#pragma unroll
    for (int n = 0; n < 4; ++n) {
      const int gc = gc0 + n * 16;
#pragma unroll
      for (int r = 0; r < 4; ++r)
        Cf[(size_t)(gr0 + m*16 + r) * N + gc] = acc[m][n][r] + bb[n];
    }
}

// ---------------- Flash attention: swapped 32x32 (R16/17 proven maps) ----------------
// Round-18 change: -m folded into the QK MFMA C-init. p comes out of the MFMA
// already equal to S - m, deleting 32 v_sub/tile in the steady (defer) path
// (the C-init movs replace the old zero-init movs 1:1). Value-equivalent
// rescale path: delta = max(rowmax_adj, 0); corr = exp2(-delta); p -= delta;
// m += delta. m starts at 0 (not -inf) so tile-0 defers when max <= 11:
// P <= 2^11, lsum <= 4.2e6, o <= ~1e7 — fp32-safe, ratio-exact at normalize.
__global__ __launch_bounds__(256) void flash32_kernel(
    const short* __restrict__ qp, const short* __restrict__ kp,
    const short* __restrict__ vt, short* __restrict__ y) {
  __shared__ char lds[32768];          // K dbuf 2x8KB | Vt dbuf 2x8KB
  char* ldsK = lds;
  char* ldsV = lds + 16384;

  const int tid = threadIdx.x, l = tid & 63, w = tid >> 6;
  const int l31 = l & 31, hi = l >> 5;

  // XCD swizzle (bijective over 1024 = 8 xcd x 8 bh x 16 qt)
  const int j0 = blockIdx.x;
  const int xcd = j0 & 7, kk0 = j0 >> 3;
  const int bh = 8 * xcd + (kk0 & 7), qt = kk0 >> 3;

  const int qrow0 = qt * 128 + w * 32;
  const short* qrow = qp + ((size_t)bh * Tn + qrow0 + l31) * Dh;
  short8 qf[4];
#pragma unroll
  for (int c = 0; c < 4; ++c)
    qf[c] = *(const short8*)&qrow[c * 16 + hi * 8];

  f32x16 o[2] = {};
  float m = 0.f, lsum = 0.f;

  const char* kb2 = (const char*)(kp + (size_t)bh * Tn * Dh);
  const char* vb2 = (const char*)(vt + (size_t)bh * Dh * Tn);
  const int sr0 = tid >> 3;            // 0..31 (row within 32-row half)
  const int swzst = (((sr0 & 7) ^ ((sr0 >> 3) << 1)) << 4);
  const int colb = (tid & 7) << 4;
  const int swzrd = (((l31 & 7) ^ ((l31 >> 3) << 1)) << 4);

#define STAGE(jt, bsel)                                                          \
  {                                                                              \
    _Pragma("unroll")                                                            \
    for (int i = 0; i < 2; ++i) {                                                \
      const int row = i * 32 + sr0;                                              \
      const int sw = colb ^ swzst;                                               \
      gload16(kb2 + (size_t)((jt) * 64 + row) * 128 + sw,                        \
              ldsK + (bsel) * 8192 + i * 4096 + tid * 16);                       \
      gload16(vb2 + (size_t)row * (Tn * 2) + (size_t)(jt) * 128 + sw,            \
              ldsV + (bsel) * 8192 + i * 4096 + tid * 16);                       \
    }                                                                            \
  }

  STAGE(0, 0);
  __syncthreads();

  for (int j = 0; j < Tn / 64; ++j) {
    const int cur = j & 1;
    if (j + 1 < Tn / 64) STAGE(j + 1, cur ^ 1);

    const char* Kb = ldsK + cur * 8192;
    const char* Vb = ldsV + cur * 8192;

    // S^T - m = K * Q^T + (-m)   (C-init = -m)
    const float negm = -m;
    f32x16 p[2];
#pragma unroll
    for (int e = 0; e < 16; ++e) { p[0][e] = negm; p[1][e] = negm; }
    __builtin_amdgcn_s_setprio(1);
#pragma unroll
    for (int t = 0; t < 2; ++t) {
      const int row = t * 32 + l31;
#pragma unroll
      for (int c = 0; c < 4; ++c) {
        short8 a = *(const short8*)(Kb + row * 128 + ((c * 32 + hi * 16) ^ swzrd));
        p[t] = mfma32(a, qf[c], p[t]);
      }
    }
    __builtin_amdgcn_s_setprio(0);

    // lane-local online softmax in adjusted domain (exp2; scale in GEMM1-LN)
    float mx = fmaxf(vmax16(p[0]), vmax16(p[1]));
    mx = fmaxf(mx, __shfl_xor(mx, 32));          // rowmax - m
    if (!__all(mx <= 11.0f)) {
      const float delta = fmaxf(mx, 0.f);
      const float corr = __builtin_amdgcn_exp2f(-delta);
      lsum *= corr;
      o[0] *= corr;
      o[1] *= corr;
      m += delta;
#pragma unroll
      for (int t = 0; t < 2; ++t)
#pragma unroll
        for (int e = 0; e < 16; ++e)
          p[t][e] -= delta;
    }
#pragma unroll
    for (int t = 0; t < 2; ++t)
#pragma unroll
      for (int e = 0; e < 16; ++e)
        p[t][e] = __builtin_amdgcn_exp2f(p[t][e]);
    {
      float ps = vsum16(p[0]) + vsum16(p[1]);
      lsum += ps + __shfl_xor(ps, 32);
    }

    // packed exchange: 16 perm + 8 shfl + 24 cndmask (R16 proven)
    short8 pf[4];
#pragma unroll
    for (int t = 0; t < 2; ++t)
#pragma unroll
      for (int f = 0; f < 2; ++f) {
        const int rb = 8 * f;
        const unsigned A0 = packtrunc(p[t][rb + 0], p[t][rb + 1]);
        const unsigned A1 = packtrunc(p[t][rb + 2], p[t][rb + 3]);
        const unsigned B0 = packtrunc(p[t][rb + 4], p[t][rb + 5]);
        const unsigned B1 = packtrunc(p[t][rb + 6], p[t][rb + 7]);
        const unsigned S0 = hi ? A0 : B0;
        const unsigned S1 = hi ? A1 : B1;
        const unsigned R0 = (unsigned)__shfl_xor((int)S0, 32);
        const unsigned R1 = (unsigned)__shfl_xor((int)S1, 32);
        i32x4 wv;
        wv[0] = (int)(hi ? R0 : A0);
        wv[1] = (int)(hi ? R1 : A1);
        wv[2] = (int)(hi ? B0 : R0);
        wv[3] = (int)(hi ? B1 : R1);
        pf[2*t + f] = __builtin_bit_cast(short8, wv);
      }

    // O^T += V^T * P^T
    __builtin_amdgcn_s_setprio(1);
#pragma unroll
    for (int dt = 0; dt < 2; ++dt) {
      const int row = dt * 32 + l31;
#pragma unroll
      for (int c = 0; c < 4; ++c) {
        short8 a = *(const short8*)(Vb + row * 128 + ((c * 32 + hi * 16) ^ swzrd));
        o[dt] = mfma32(a, pf[c], o[dt]);
      }
    }
    __builtin_amdgcn_s_setprio(0);

    __syncthreads();
  }
#undef STAGE

  // epilogue: lane-local normalize, direct 8B stores
  const float rl = 1.0f / lsum;
  const int b = bh >> 4, hh = bh & 15;
  const int t = qrow0 + l31;
  short* yrow = y + ((size_t)(b * Tn + t)) * En + hh * 64;
#pragma unroll
  for (int dt = 0; dt < 2; ++dt)
#pragma unroll
    for (int g = 0; g < 4; ++g) {
      short4v v4;
#pragma unroll
      for (int i = 0; i < 4; ++i) v4[i] = f2b(o[dt][g*4 + i] * rl);
      *(short4v*)&yrow[dt*32 + g*8 + hi*4] = v4;
    }
}

extern "C" void kernel_launch(void* const* d_in, const int* in_sizes, int n_in,
                              void* d_out, int out_size, void* d_ws, size_t ws_size,
                              hipStream_t stream) {
  const float* x     = (const float*)d_in[0];
  const float* Wqkv  = (const float*)d_in[1];
  const float* bqkv  = (const float*)d_in[2];
  const float* qg    = (const float*)d_in[3];
  const float* qb    = (const float*)d_in[4];
  const float* kg    = (const float*)d_in[5];
  const float* kb    = (const float*)d_in[6];
  const float* Wproj = (const float*)d_in[7];
  const float* bproj = (const float*)d_in[8];
  float* out = (float*)d_out;

  char* p = (char*)d_ws;
  short* xb     = (short*)p; p += (size_t)Mn * Kn * 2;
  short* wqkvT  = (short*)p; p += (size_t)N1 * Kn * 2;
  short* wprojT = (short*)p; p += (size_t)En * Kn * 2;
  short* qp     = (short*)p; p += (size_t)Mn * Kn * 2;
  short* kp     = (short*)p; p += (size_t)Mn * Kn * 2;
  short* vtb    = (short*)p; p += (size_t)Mn * Kn * 2;
  short* yb     = (short*)p; p += (size_t)Mn * Kn * 2;

  prep_kernel<<<8192, 256, 0, stream>>>(x, xb, Wqkv, wqkvT, Wproj, wprojT);
  gemm1_kernel<<<(N1 / 128) * (Mn / 128), 256, 0, stream>>>(
      xb, wqkvT, bqkv, qp, kp, vtb, qg, qb, kg, kb,
      N1 / 128, (N1 / 128) * (Mn / 128) / 8);
  flash32_kernel<<<1024, 256, 0, stream>>>(qp, kp, vtb, yb);
  gemm2_kernel<<<(En / 128) * (Mn / 64), 256, 0, stream>>>(
      yb, wprojT, bproj, out, En, En / 128, (En / 128) * (Mn / 64) / 8);
}

// Round 19
// 236.515 us; speedup vs baseline: 1.0101x; 1.0101x over previous
//
#include <hip/hip_runtime.h>

// Problem constants
#define Hn  16
#define Dh  64
#define Bb  4
#define Tn  2048
#define En  1024
#define Mn  8192           // B*T
#define N1  3072           // 3*E
#define Kn  1024           // E

typedef __attribute__((ext_vector_type(8)))  short  short8;
typedef __attribute__((ext_vector_type(4)))  short  short4v;
typedef __attribute__((ext_vector_type(4)))  float  f32x4;
typedef __attribute__((ext_vector_type(16))) float  f32x16;
typedef __attribute__((ext_vector_type(8)))  __bf16 bf16x8;
typedef __attribute__((ext_vector_type(4)))  int    i32x4;

__device__ __forceinline__ float b2f(short s) {
  unsigned u = ((unsigned)(unsigned short)s) << 16;
  return __builtin_bit_cast(float, u);
}
__device__ __forceinline__ short f2b(float f) {
  unsigned u = __builtin_bit_cast(unsigned, f);
  u += 0x7fffu + ((u >> 16) & 1u);
  return (short)(u >> 16);
}
__device__ __forceinline__ f32x4 mfma16(short8 a, short8 b, f32x4 c) {
  return __builtin_amdgcn_mfma_f32_16x16x32_bf16(
      __builtin_bit_cast(bf16x8, a), __builtin_bit_cast(bf16x8, b), c, 0, 0, 0);
}
__device__ __forceinline__ f32x16 mfma32(short8 a, short8 b, f32x16 c) {
  return __builtin_amdgcn_mfma_f32_32x32x16_bf16(
      __builtin_bit_cast(bf16x8, a), __builtin_bit_cast(bf16x8, b), c, 0, 0, 0);
}
__device__ __forceinline__ void gload16(const void* g, void* l) {
  __builtin_amdgcn_global_load_lds(
      (const __attribute__((address_space(1))) unsigned int*)g,
      (__attribute__((address_space(3))) unsigned int*)l, 16, 0, 0);
}
// pack two f32 into (hi16(b)<<16 | hi16(a)) with one v_perm_b32
__device__ __forceinline__ unsigned packtrunc(float a, float b) {
  return __builtin_amdgcn_perm(__builtin_bit_cast(unsigned, b),
                               __builtin_bit_cast(unsigned, a), 0x07060302u);
}
// max tree as nested triples -> v_max3_f32 fusion; bit-exact (max associative)
__device__ __forceinline__ float vmax16(f32x16 v) {
  float a0 = fmaxf(fmaxf(v[0],  v[1]),  v[2]);
  float a1 = fmaxf(fmaxf(v[3],  v[4]),  v[5]);
  float a2 = fmaxf(fmaxf(v[6],  v[7]),  v[8]);
  float a3 = fmaxf(fmaxf(v[9],  v[10]), v[11]);
  float a4 = fmaxf(fmaxf(v[12], v[13]), v[14]);
  float b0 = fmaxf(fmaxf(a0, a1), a2);
  float b1 = fmaxf(fmaxf(a3, a4), v[15]);
  return fmaxf(b0, b1);
}
__device__ __forceinline__ float vsum16(f32x16 v) {
  float a0 = v[0]+v[1], a1 = v[2]+v[3], a2 = v[4]+v[5], a3 = v[6]+v[7];
  float a4 = v[8]+v[9], a5 = v[10]+v[11], a6 = v[12]+v[13], a7 = v[14]+v[15];
  return ((a0+a1)+(a2+a3)) + ((a4+a5)+(a6+a7));
}

// ---------------- merged preprocessing: cvt_x + transpose both W ----------------
__global__ __launch_bounds__(256) void prep_kernel(
    const float* __restrict__ x, short* __restrict__ xb,
    const float* __restrict__ Wqkv, short* __restrict__ wqkvT,
    const float* __restrict__ Wproj, short* __restrict__ wprojT) {
  __shared__ float tile[32][33];
  const int bid = blockIdx.x, tid = threadIdx.x;
  if (bid < 4096) {
    const size_t i = ((size_t)bid * 256 + tid) * 8;
    f32x4 a = *(const f32x4*)&x[i];
    f32x4 b = *(const f32x4*)&x[i + 4];
    short8 o;
    o[0]=f2b(a[0]); o[1]=f2b(a[1]); o[2]=f2b(a[2]); o[3]=f2b(a[3]);
    o[4]=f2b(b[0]); o[5]=f2b(b[1]); o[6]=f2b(b[2]); o[7]=f2b(b[3]);
    *(short8*)&xb[i] = o;
    return;
  }
  const float* in; short* out; int R, C, bx, by;
  if (bid < 4096 + 3072) {
    const int b2 = bid - 4096;
    in = Wqkv; out = wqkvT; R = Kn; C = N1; bx = b2 % 96; by = b2 / 96;
  } else {
    const int b3 = bid - 7168;
    in = Wproj; out = wprojT; R = Kn; C = En; bx = b3 % 32; by = b3 / 32;
  }
  const int c0 = bx * 32, r0 = by * 32;
  const int lr = tid >> 3, lc = (tid & 7) * 4;
  f32x4 v = *(const f32x4*)&in[(size_t)(r0 + lr) * C + c0 + lc];
  tile[lr][lc] = v[0]; tile[lr][lc+1] = v[1]; tile[lr][lc+2] = v[2]; tile[lr][lc+3] = v[3];
  __syncthreads();
  const int oc = tid >> 3, orr = (tid & 7) * 4;
  short4v ov;
  ov[0] = f2b(tile[orr][oc]);   ov[1] = f2b(tile[orr+1][oc]);
  ov[2] = f2b(tile[orr+2][oc]); ov[3] = f2b(tile[orr+3][oc]);
  *(short4v*)&out[(size_t)(c0 + oc) * R + r0 + orr] = ov;
}

// ---------------- GEMM1 (round-13 proven: fused LN + coalesced epilogue) ----------------
__global__ __launch_bounds__(256) void gemm1_kernel(
    const short* __restrict__ A, const short* __restrict__ Bt,
    const float* __restrict__ bias,
    short* __restrict__ qo, short* __restrict__ ko2, short* __restrict__ vo,
    const float* __restrict__ qg, const float* __restrict__ qb,
    const float* __restrict__ kg, const float* __restrict__ kb,
    int NBX, int cpx) {
  __shared__ short S[8192];
  const int lin = blockIdx.x;
  const int swz = (lin & 7) * cpx + (lin >> 3);
  const int bx = swz % NBX, by = swz / NBX;
  const int tid = threadIdx.x, lane = tid & 63, w = tid >> 6;
  const int rowBase = by * 128, colBase = bx * 128;
  f32x4 acc[4][4] = {};
  const int srow = tid >> 2, sk = (tid & 3) << 3;
  const short* Ag = A  + (size_t)(rowBase + srow) * Kn + sk;
  const short* Bg = Bt + (size_t)(colBase + srow) * Kn + sk;
  short* AsW = S + w * 512;
  short* BsW = S + 4096 + w * 512;
  const int ar = (w >> 1) * 64, bc = (w & 1) * 64;
  const int lg = lane >> 4, lg8 = lg * 8, lr = lane & 15;

  for (int kt = 0; kt < Kn; kt += 32) {
    __syncthreads();
    gload16(Ag + kt,            AsW);
    gload16(Ag + kt + 64 * Kn,  AsW + 2048);
    gload16(Bg + kt,            BsW);
    gload16(Bg + kt + 64 * Kn,  BsW + 2048);
    __syncthreads();
    short8 af[4], bfr[4];
#pragma unroll
    for (int m = 0; m < 4; ++m) af[m]  = *(const short8*)&S[(ar + m*16 + lr)*32 + lg8];
#pragma unroll
    for (int n = 0; n < 4; ++n) bfr[n] = *(const short8*)&S[4096 + (bc + n*16 + lr)*32 + lg8];
#pragma unroll
    for (int m = 0; m < 4; ++m)
#pragma unroll
      for (int n = 0; n < 4; ++n)
        acc[m][n] = mfma16(af[m], bfr[n], acc[m][n]);
  }

  const int gr0 = rowBase + ar + lg * 4;
  const int gc0 = colBase + bc + lr;

  float bb[4];
#pragma unroll
  for (int n = 0; n < 4; ++n) bb[n] = bias[gc0 + n * 16];
#pragma unroll
  for (int m = 0; m < 4; ++m)
#pragma unroll
    for (int n = 0; n < 4; ++n)
#pragma unroll
      for (int r = 0; r < 4; ++r) acc[m][n][r] += bb[n];

  const int which = colBase >> 10;            // block-uniform: 0=q 1=k 2=v
  if (which < 2) {
    const float* gp = (which == 0) ? qg : kg;
    const float* bp = (which == 0) ? qb : kb;
    const float sc = (which == 0) ? 0.1803368801111204f : 1.0f;  // 0.125*log2(e)
    float gam[4], bet[4];
#pragma unroll
    for (int n = 0; n < 4; ++n) { gam[n] = gp[n * 16 + lr]; bet[n] = bp[n * 16 + lr]; }
#pragma unroll
    for (int m = 0; m < 4; ++m)
#pragma unroll
      for (int r = 0; r < 4; ++r) {
        float s1 = 0.f, s2 = 0.f;
#pragma unroll
        for (int n = 0; n < 4; ++n) {
          const float v = acc[m][n][r];
          s1 += v; s2 += v * v;
        }
#pragma unroll
        for (int off = 1; off < 16; off <<= 1) {
          s1 += __shfl_xor(s1, off);
          s2 += __shfl_xor(s2, off);
        }
        const float mu = s1 * 0.015625f;
        const float rs = rsqrtf(s2 * 0.015625f - mu * mu + 1e-5f);
#pragma unroll
        for (int n = 0; n < 4; ++n)
          acc[m][n][r] = ((acc[m][n][r] - mu) * rs * gam[n] + bet[n]) * sc;
      }
  }

  __syncthreads();
  short* Sw = S + w * 2048;
  const int t0 = (rowBase & 2047) + ar;
  const int bidx = (rowBase + ar) >> 11;
  const int hh = ((colBase + bc) & 1023) >> 6;
  const int bh = bidx * Hn + hh;
  const int l8 = lane & 7, ld8 = lane >> 3;

  if (which < 2) {
    short* dst0 = (which == 0) ? qo : ko2;
#pragma unroll
    for (int p = 0; p < 2; ++p) {
#pragma unroll
      for (int mm = 0; mm < 2; ++mm) {
        const int m = p * 2 + mm;
#pragma unroll
        for (int n = 0; n < 4; ++n)
#pragma unroll
          for (int r = 0; r < 4; ++r) {
            const int tl = mm*16 + lg*4 + r;
            const int dl = n*16 + lr;
            Sw[tl*64 + (dl ^ ((tl & 7) << 3))] = f2b(acc[m][n][r]);
          }
      }
#pragma unroll
      for (int i = 0; i < 4; ++i) {
        const int tl = i*8 + ld8;
        short8 v = *(const short8*)&Sw[tl*64 + ((l8*8) ^ ((tl & 7) << 3))];
        const int t = t0 + p*32 + tl;
        *(short8*)&dst0[((size_t)bh * Tn + t) * Dh + l8*8] = v;
      }
    }
  } else {
#pragma unroll
    for (int p = 0; p < 2; ++p) {
#pragma unroll
      for (int nn = 0; nn < 2; ++nn) {
        const int n = p * 2 + nn;
#pragma unroll
        for (int m = 0; m < 4; ++m)
#pragma unroll
          for (int r = 0; r < 4; ++r) {
            const int dl = nn*16 + lr;
            const int tc = m*16 + lg*4 + r;
            Sw[dl*64 + (tc ^ ((dl & 7) << 3))] = f2b(acc[m][n][r]);
          }
      }
#pragma unroll
      for (int i = 0; i < 4; ++i) {
        const int dl = i*8 + ld8;
        short8 v = *(const short8*)&Sw[dl*64 + ((l8*8) ^ ((dl & 7) << 3))];
        const int d = p*32 + dl;
        *(short8*)&vo[((size_t)bh * Dh + d) * Tn + t0 + l8*8] = v;
      }
    }
  }
}

// ---------------- GEMM2: 64x128 tiles (round-17 proven) ----------------
__global__ __launch_bounds__(256) void gemm2_kernel(
    const short* __restrict__ A, const short* __restrict__ Bt,
    const float* __restrict__ bias, float* __restrict__ Cf,
    int N, int NBX, int cpx) {
  __shared__ short S[6144];     // A 64x32 (2048 sh) | B 128x32 (4096 sh)
  const int lin = blockIdx.x;
  const int swz = (lin & 7) * cpx + (lin >> 3);
  const int bx = swz % NBX, by = swz / NBX;
  const int tid = threadIdx.x, lane = tid & 63, w = tid >> 6;
  const int rowBase = by * 64, colBase = bx * 128;
  f32x4 acc[2][4] = {};
  const int srow = tid >> 2, sk = (tid & 3) << 3;
  const short* Ag = A  + (size_t)(rowBase + srow) * Kn + sk;
  const short* Bg = Bt + (size_t)(colBase + srow) * Kn + sk;
  const int ar = (w >> 1) * 32, bc = (w & 1) * 64;
  const int lg = lane >> 4, lg8 = lg * 8, lr = lane & 15;

  for (int kt = 0; kt < Kn; kt += 32) {
    __syncthreads();
    gload16(Ag + kt,            S + w * 512);          // A rows 0..63
    gload16(Bg + kt,            S + 2048 + w * 512);   // B rows 0..63
    gload16(Bg + kt + 64 * Kn,  S + 4096 + w * 512);   // B rows 64..127
    __syncthreads();
    short8 af[2], bfr[4];
#pragma unroll
    for (int m = 0; m < 2; ++m) af[m]  = *(const short8*)&S[(ar + m*16 + lr)*32 + lg8];
#pragma unroll
    for (int n = 0; n < 4; ++n) bfr[n] = *(const short8*)&S[2048 + (bc + n*16 + lr)*32 + lg8];
#pragma unroll
    for (int m = 0; m < 2; ++m)
#pragma unroll
      for (int n = 0; n < 4; ++n)
        acc[m][n] = mfma16(af[m], bfr[n], acc[m][n]);
  }

  const int gr0 = rowBase + ar + lg * 4;
  const int gc0 = colBase + bc + lr;
  float bb[4];
#pragma unroll
  for (int n = 0; n < 4; ++n) bb[n] = bias[gc0 + n * 16];
#pragma unroll
  for (int m = 0; m < 2; ++m)
#pragma unroll
    for (int n = 0; n < 4; ++n) {
      const int gc = gc0 + n * 16;
#pragma unroll
      for (int r = 0; r < 4; ++r)
        Cf[(size_t)(gr0 + m*16 + r) * N + gc] = acc[m][n][r] + bb[n];
    }
}

// ---------------- Flash attention: swapped 32x32 (R16/R17 proven, restored) ----------------
__global__ __launch_bounds__(256) void flash32_kernel(
    const short* __restrict__ qp, const short* __restrict__ kp,
    const short* __restrict__ vt, short* __restrict__ y) {
  __shared__ char lds[32768];          // K dbuf 2x8KB | Vt dbuf 2x8KB
  char* ldsK = lds;
  char* ldsV = lds + 16384;

  const int tid = threadIdx.x, l = tid & 63, w = tid >> 6;
  const int l31 = l & 31, hi = l >> 5;

  // XCD swizzle (bijective over 1024 = 8 xcd x 8 bh x 16 qt)
  const int j0 = blockIdx.x;
  const int xcd = j0 & 7, kk0 = j0 >> 3;
  const int bh = 8 * xcd + (kk0 & 7), qt = kk0 >> 3;

  const int qrow0 = qt * 128 + w * 32;
  const short* qrow = qp + ((size_t)bh * Tn + qrow0 + l31) * Dh;
  short8 qf[4];
#pragma unroll
  for (int c = 0; c < 4; ++c)
    qf[c] = *(const short8*)&qrow[c * 16 + hi * 8];

  f32x16 o[2] = {};
  float m = -1e30f, lsum = 0.f;

  const char* kb2 = (const char*)(kp + (size_t)bh * Tn * Dh);
  const char* vb2 = (const char*)(vt + (size_t)bh * Dh * Tn);
  const int sr0 = tid >> 3;            // 0..31 (row within 32-row half)
  const int swzst = (((sr0 & 7) ^ ((sr0 >> 3) << 1)) << 4);
  const int colb = (tid & 7) << 4;
  const int swzrd = (((l31 & 7) ^ ((l31 >> 3) << 1)) << 4);

#define STAGE(jt, bsel)                                                          \
  {                                                                              \
    _Pragma("unroll")                                                            \
    for (int i = 0; i < 2; ++i) {                                                \
      const int row = i * 32 + sr0;                                              \
      const int sw = colb ^ swzst;                                               \
      gload16(kb2 + (size_t)((jt) * 64 + row) * 128 + sw,                        \
              ldsK + (bsel) * 8192 + i * 4096 + tid * 16);                       \
      gload16(vb2 + (size_t)row * (Tn * 2) + (size_t)(jt) * 128 + sw,            \
              ldsV + (bsel) * 8192 + i * 4096 + tid * 16);                       \
    }                                                                            \
  }

  STAGE(0, 0);
  __syncthreads();

  for (int j = 0; j < Tn / 64; ++j) {
    const int cur = j & 1;
    if (j + 1 < Tn / 64) STAGE(j + 1, cur ^ 1);

    const char* Kb = ldsK + cur * 8192;
    const char* Vb = ldsV + cur * 8192;

    // S^T = K * Q^T
    f32x16 p[2] = {};
    __builtin_amdgcn_s_setprio(1);
#pragma unroll
    for (int t = 0; t < 2; ++t) {
      const int row = t * 32 + l31;
#pragma unroll
      for (int c = 0; c < 4; ++c) {
        short8 a = *(const short8*)(Kb + row * 128 + ((c * 32 + hi * 16) ^ swzrd));
        p[t] = mfma32(a, qf[c], p[t]);
      }
    }
    __builtin_amdgcn_s_setprio(0);

    // lane-local online softmax (exp2 domain; scale folded in GEMM1-LN)
    float mx = fmaxf(vmax16(p[0]), vmax16(p[1]));
    mx = fmaxf(mx, __shfl_xor(mx, 32));
    if (!__all(mx - m <= 11.0f)) {
      const float mn = fmaxf(m, mx);
      const float corr = __builtin_amdgcn_exp2f(m - mn);
      lsum *= corr;
      o[0] *= corr;
      o[1] *= corr;
      m = mn;
    }
#pragma unroll
    for (int t = 0; t < 2; ++t)
#pragma unroll
      for (int e = 0; e < 16; ++e)
        p[t][e] = __builtin_amdgcn_exp2f(p[t][e] - m);
    {
      float ps = vsum16(p[0]) + vsum16(p[1]);
      lsum += ps + __shfl_xor(ps, 32);
    }

    // packed exchange: 16 perm + 8 shfl + 24 cndmask (R16 proven)
    short8 pf[4];
#pragma unroll
    for (int t = 0; t < 2; ++t)
#pragma unroll
      for (int f = 0; f < 2; ++f) {
        const int rb = 8 * f;
        const unsigned A0 = packtrunc(p[t][rb + 0], p[t][rb + 1]);
        const unsigned A1 = packtrunc(p[t][rb + 2], p[t][rb + 3]);
        const unsigned B0 = packtrunc(p[t][rb + 4], p[t][rb + 5]);
        const unsigned B1 = packtrunc(p[t][rb + 6], p[t][rb + 7]);
        const unsigned S0 = hi ? A0 : B0;
        const unsigned S1 = hi ? A1 : B1;
        const unsigned R0 = (unsigned)__shfl_xor((int)S0, 32);
        const unsigned R1 = (unsigned)__shfl_xor((int)S1, 32);
        i32x4 wv;
        wv[0] = (int)(hi ? R0 : A0);
        wv[1] = (int)(hi ? R1 : A1);
        wv[2] = (int)(hi ? B0 : R0);
        wv[3] = (int)(hi ? B1 : R1);
        pf[2*t + f] = __builtin_bit_cast(short8, wv);
      }

    // O^T += V^T * P^T
    __builtin_amdgcn_s_setprio(1);
#pragma unroll
    for (int dt = 0; dt < 2; ++dt) {
      const int row = dt * 32 + l31;
#pragma unroll
      for (int c = 0; c < 4; ++c) {
        short8 a = *(const short8*)(Vb + row * 128 + ((c * 32 + hi * 16) ^ swzrd));
        o[dt] = mfma32(a, pf[c], o[dt]);
      }
    }
    __builtin_amdgcn_s_setprio(0);

    __syncthreads();
  }
#undef STAGE

  // epilogue: lane-local normalize, direct 8B stores
  const float rl = 1.0f / lsum;
  const int b = bh >> 4, hh = bh & 15;
  const int t = qrow0 + l31;
  short* yrow = y + ((size_t)(b * Tn + t)) * En + hh * 64;
#pragma unroll
  for (int dt = 0; dt < 2; ++dt)
#pragma unroll
    for (int g = 0; g < 4; ++g) {
      short4v v4;
#pragma unroll
      for (int i = 0; i < 4; ++i) v4[i] = f2b(o[dt][g*4 + i] * rl);
      *(short4v*)&yrow[dt*32 + g*8 + hi*4] = v4;
    }
}

extern "C" void kernel_launch(void* const* d_in, const int* in_sizes, int n_in,
                              void* d_out, int out_size, void* d_ws, size_t ws_size,
                              hipStream_t stream) {
  const float* x     = (const float*)d_in[0];
  const float* Wqkv  = (const float*)d_in[1];
  const float* bqkv  = (const float*)d_in[2];
  const float* qg    = (const float*)d_in[3];
  const float* qb    = (const float*)d_in[4];
  const float* kg    = (const float*)d_in[5];
  const float* kb    = (const float*)d_in[6];
  const float* Wproj = (const float*)d_in[7];
  const float* bproj = (const float*)d_in[8];
  float* out = (float*)d_out;

  char* p = (char*)d_ws;
  short* xb     = (short*)p; p += (size_t)Mn * Kn * 2;
  short* wqkvT  = (short*)p; p += (size_t)N1 * Kn * 2;
  short* wprojT = (short*)p; p += (size_t)En * Kn * 2;
  short* qp     = (short*)p; p += (size_t)Mn * Kn * 2;
  short* kp     = (short*)p; p += (size_t)Mn * Kn * 2;
  short* vtb    = (short*)p; p += (size_t)Mn * Kn * 2;
  short* yb     = (short*)p; p += (size_t)Mn * Kn * 2;

  prep_kernel<<<8192, 256, 0, stream>>>(x, xb, Wqkv, wqkvT, Wproj, wprojT);
  gemm1_kernel<<<(N1 / 128) * (Mn / 128), 256, 0, stream>>>(
      xb, wqkvT, bqkv, qp, kp, vtb, qg, qb, kg, kb,
      N1 / 128, (N1 / 128) * (Mn / 128) / 8);
  flash32_kernel<<<1024, 256, 0, stream>>>(qp, kp, vtb, yb);
  gemm2_kernel<<<(En / 128) * (Mn / 64), 256, 0, stream>>>(
      yb, wprojT, bproj, out, En, En / 128, (En / 128) * (Mn / 64) / 8);
}

// Round 20
// 233.267 us; speedup vs baseline: 1.0241x; 1.0139x over previous
//
#include <hip/hip_runtime.h>

// Problem constants
#define Hn  16
#define Dh  64
#define Bb  4
#define Tn  2048
#define En  1024
#define Mn  8192           // B*T
#define N1  3072           // 3*E
#define Kn  1024           // E

typedef __attribute__((ext_vector_type(8)))  short  short8;
typedef __attribute__((ext_vector_type(4)))  short  short4v;
typedef __attribute__((ext_vector_type(4)))  float  f32x4;
typedef __attribute__((ext_vector_type(16))) float  f32x16;
typedef __attribute__((ext_vector_type(8)))  __bf16 bf16x8;
typedef __attribute__((ext_vector_type(4)))  int    i32x4;

__device__ __forceinline__ float b2f(short s) {
  unsigned u = ((unsigned)(unsigned short)s) << 16;
  return __builtin_bit_cast(float, u);
}
__device__ __forceinline__ short f2b(float f) {
  unsigned u = __builtin_bit_cast(unsigned, f);
  u += 0x7fffu + ((u >> 16) & 1u);
  return (short)(u >> 16);
}
__device__ __forceinline__ f32x4 mfma16(short8 a, short8 b, f32x4 c) {
  return __builtin_amdgcn_mfma_f32_16x16x32_bf16(
      __builtin_bit_cast(bf16x8, a), __builtin_bit_cast(bf16x8, b), c, 0, 0, 0);
}
__device__ __forceinline__ f32x16 mfma32(short8 a, short8 b, f32x16 c) {
  return __builtin_amdgcn_mfma_f32_32x32x16_bf16(
      __builtin_bit_cast(bf16x8, a), __builtin_bit_cast(bf16x8, b), c, 0, 0, 0);
}
__device__ __forceinline__ void gload16(const void* g, void* l) {
  __builtin_amdgcn_global_load_lds(
      (const __attribute__((address_space(1))) unsigned int*)g,
      (__attribute__((address_space(3))) unsigned int*)l, 16, 0, 0);
}
// pack two f32 into (hi16(b)<<16 | hi16(a)) with one v_perm_b32
__device__ __forceinline__ unsigned packtrunc(float a, float b) {
  return __builtin_amdgcn_perm(__builtin_bit_cast(unsigned, b),
                               __builtin_bit_cast(unsigned, a), 0x07060302u);
}
// max tree as nested triples -> v_max3_f32 fusion; bit-exact (max associative)
__device__ __forceinline__ float vmax16(f32x16 v) {
  float a0 = fmaxf(fmaxf(v[0],  v[1]),  v[2]);
  float a1 = fmaxf(fmaxf(v[3],  v[4]),  v[5]);
  float a2 = fmaxf(fmaxf(v[6],  v[7]),  v[8]);
  float a3 = fmaxf(fmaxf(v[9],  v[10]), v[11]);
  float a4 = fmaxf(fmaxf(v[12], v[13]), v[14]);
  float b0 = fmaxf(fmaxf(a0, a1), a2);
  float b1 = fmaxf(fmaxf(a3, a4), v[15]);
  return fmaxf(b0, b1);
}
__device__ __forceinline__ float vsum16(f32x16 v) {
  float a0 = v[0]+v[1], a1 = v[2]+v[3], a2 = v[4]+v[5], a3 = v[6]+v[7];
  float a4 = v[8]+v[9], a5 = v[10]+v[11], a6 = v[12]+v[13], a7 = v[14]+v[15];
  return ((a0+a1)+(a2+a3)) + ((a4+a5)+(a6+a7));
}

// ---------------- merged preprocessing: cvt_x + transpose both W ----------------
__global__ __launch_bounds__(256) void prep_kernel(
    const float* __restrict__ x, short* __restrict__ xb,
    const float* __restrict__ Wqkv, short* __restrict__ wqkvT,
    const float* __restrict__ Wproj, short* __restrict__ wprojT) {
  __shared__ float tile[32][33];
  const int bid = blockIdx.x, tid = threadIdx.x;
  if (bid < 4096) {
    const size_t i = ((size_t)bid * 256 + tid) * 8;
    f32x4 a = *(const f32x4*)&x[i];
    f32x4 b = *(const f32x4*)&x[i + 4];
    short8 o;
    o[0]=f2b(a[0]); o[1]=f2b(a[1]); o[2]=f2b(a[2]); o[3]=f2b(a[3]);
    o[4]=f2b(b[0]); o[5]=f2b(b[1]); o[6]=f2b(b[2]); o[7]=f2b(b[3]);
    *(short8*)&xb[i] = o;
    return;
  }
  const float* in; short* out; int R, C, bx, by;
  if (bid < 4096 + 3072) {
    const int b2 = bid - 4096;
    in = Wqkv; out = wqkvT; R = Kn; C = N1; bx = b2 % 96; by = b2 / 96;
  } else {
    const int b3 = bid - 7168;
    in = Wproj; out = wprojT; R = Kn; C = En; bx = b3 % 32; by = b3 / 32;
  }
  const int c0 = bx * 32, r0 = by * 32;
  const int lr = tid >> 3, lc = (tid & 7) * 4;
  f32x4 v = *(const f32x4*)&in[(size_t)(r0 + lr) * C + c0 + lc];
  tile[lr][lc] = v[0]; tile[lr][lc+1] = v[1]; tile[lr][lc+2] = v[2]; tile[lr][lc+3] = v[3];
  __syncthreads();
  const int oc = tid >> 3, orr = (tid & 7) * 4;
  short4v ov;
  ov[0] = f2b(tile[orr][oc]);   ov[1] = f2b(tile[orr+1][oc]);
  ov[2] = f2b(tile[orr+2][oc]); ov[3] = f2b(tile[orr+3][oc]);
  *(short4v*)&out[(size_t)(c0 + oc) * R + r0 + orr] = ov;
}

// ---------------- GEMM1 (round-13 proven: fused LN + coalesced epilogue) ----------------
__global__ __launch_bounds__(256) void gemm1_kernel(
    const short* __restrict__ A, const short* __restrict__ Bt,
    const float* __restrict__ bias,
    short* __restrict__ qo, short* __restrict__ ko2, short* __restrict__ vo,
    const float* __restrict__ qg, const float* __restrict__ qb,
    const float* __restrict__ kg, const float* __restrict__ kb,
    int NBX, int cpx) {
  __shared__ short S[8192];
  const int lin = blockIdx.x;
  const int swz = (lin & 7) * cpx + (lin >> 3);
  const int bx = swz % NBX, by = swz / NBX;
  const int tid = threadIdx.x, lane = tid & 63, w = tid >> 6;
  const int rowBase = by * 128, colBase = bx * 128;
  f32x4 acc[4][4] = {};
  const int srow = tid >> 2, sk = (tid & 3) << 3;
  const short* Ag = A  + (size_t)(rowBase + srow) * Kn + sk;
  const short* Bg = Bt + (size_t)(colBase + srow) * Kn + sk;
  short* AsW = S + w * 512;
  short* BsW = S + 4096 + w * 512;
  const int ar = (w >> 1) * 64, bc = (w & 1) * 64;
  const int lg = lane >> 4, lg8 = lg * 8, lr = lane & 15;

  for (int kt = 0; kt < Kn; kt += 32) {
    __syncthreads();
    gload16(Ag + kt,            AsW);
    gload16(Ag + kt + 64 * Kn,  AsW + 2048);
    gload16(Bg + kt,            BsW);
    gload16(Bg + kt + 64 * Kn,  BsW + 2048);
    __syncthreads();
    short8 af[4], bfr[4];
#pragma unroll
    for (int m = 0; m < 4; ++m) af[m]  = *(const short8*)&S[(ar + m*16 + lr)*32 + lg8];
#pragma unroll
    for (int n = 0; n < 4; ++n) bfr[n] = *(const short8*)&S[4096 + (bc + n*16 + lr)*32 + lg8];
#pragma unroll
    for (int m = 0; m < 4; ++m)
#pragma unroll
      for (int n = 0; n < 4; ++n)
        acc[m][n] = mfma16(af[m], bfr[n], acc[m][n]);
  }

  const int gr0 = rowBase + ar + lg * 4;
  const int gc0 = colBase + bc + lr;

  float bb[4];
#pragma unroll
  for (int n = 0; n < 4; ++n) bb[n] = bias[gc0 + n * 16];
#pragma unroll
  for (int m = 0; m < 4; ++m)
#pragma unroll
    for (int n = 0; n < 4; ++n)
#pragma unroll
      for (int r = 0; r < 4; ++r) acc[m][n][r] += bb[n];

  const int which = colBase >> 10;            // block-uniform: 0=q 1=k 2=v
  if (which < 2) {
    const float* gp = (which == 0) ? qg : kg;
    const float* bp = (which == 0) ? qb : kb;
    const float sc = (which == 0) ? 0.1803368801111204f : 1.0f;  // 0.125*log2(e)
    float gam[4], bet[4];
#pragma unroll
    for (int n = 0; n < 4; ++n) { gam[n] = gp[n * 16 + lr]; bet[n] = bp[n * 16 + lr]; }
#pragma unroll
    for (int m = 0; m < 4; ++m)
#pragma unroll
      for (int r = 0; r < 4; ++r) {
        float s1 = 0.f, s2 = 0.f;
#pragma unroll
        for (int n = 0; n < 4; ++n) {
          const float v = acc[m][n][r];
          s1 += v; s2 += v * v;
        }
#pragma unroll
        for (int off = 1; off < 16; off <<= 1) {
          s1 += __shfl_xor(s1, off);
          s2 += __shfl_xor(s2, off);
        }
        const float mu = s1 * 0.015625f;
        const float rs = rsqrtf(s2 * 0.015625f - mu * mu + 1e-5f);
#pragma unroll
        for (int n = 0; n < 4; ++n)
          acc[m][n][r] = ((acc[m][n][r] - mu) * rs * gam[n] + bet[n]) * sc;
      }
  }

  __syncthreads();
  short* Sw = S + w * 2048;
  const int t0 = (rowBase & 2047) + ar;
  const int bidx = (rowBase + ar) >> 11;
  const int hh = ((colBase + bc) & 1023) >> 6;
  const int bh = bidx * Hn + hh;
  const int l8 = lane & 7, ld8 = lane >> 3;

  if (which < 2) {
    short* dst0 = (which == 0) ? qo : ko2;
#pragma unroll
    for (int p = 0; p < 2; ++p) {
#pragma unroll
      for (int mm = 0; mm < 2; ++mm) {
        const int m = p * 2 + mm;
#pragma unroll
        for (int n = 0; n < 4; ++n)
#pragma unroll
          for (int r = 0; r < 4; ++r) {
            const int tl = mm*16 + lg*4 + r;
            const int dl = n*16 + lr;
            Sw[tl*64 + (dl ^ ((tl & 7) << 3))] = f2b(acc[m][n][r]);
          }
      }
#pragma unroll
      for (int i = 0; i < 4; ++i) {
        const int tl = i*8 + ld8;
        short8 v = *(const short8*)&Sw[tl*64 + ((l8*8) ^ ((tl & 7) << 3))];
        const int t = t0 + p*32 + tl;
        *(short8*)&dst0[((size_t)bh * Tn + t) * Dh + l8*8] = v;
      }
    }
  } else {
#pragma unroll
    for (int p = 0; p < 2; ++p) {
#pragma unroll
      for (int nn = 0; nn < 2; ++nn) {
        const int n = p * 2 + nn;
#pragma unroll
        for (int m = 0; m < 4; ++m)
#pragma unroll
          for (int r = 0; r < 4; ++r) {
            const int dl = nn*16 + lr;
            const int tc = m*16 + lg*4 + r;
            Sw[dl*64 + (tc ^ ((dl & 7) << 3))] = f2b(acc[m][n][r]);
          }
      }
#pragma unroll
      for (int i = 0; i < 4; ++i) {
        const int dl = i*8 + ld8;
        short8 v = *(const short8*)&Sw[dl*64 + ((l8*8) ^ ((dl & 7) << 3))];
        const int d = p*32 + dl;
        *(short8*)&vo[((size_t)bh * Dh + d) * Tn + t0 + l8*8] = v;
      }
    }
  }
}

// ---------------- GEMM2: 64x128 tiles, BK=64 (one barrier pair per 64-k step) ----------------
// Bit-exact vs BK=32 (same per-element k-order). LDS rows are 128B so a
// 16B-granule XOR swizzle (col ^ (row&7)<<3 shorts) is REQUIRED (G4);
// applied G21-style: pre-swizzled per-lane global source + same XOR on reads;
// staging dest stays wave-linear (base + lane*16, m104-safe).
__global__ __launch_bounds__(256) void gemm2_kernel(
    const short* __restrict__ A, const short* __restrict__ Bt,
    const float* __restrict__ bias, float* __restrict__ Cf,
    int N, int NBX, int cpx) {
  __shared__ short S[12288];    // A [64][64] @0 | B [128][64] @4096
  const int lin = blockIdx.x;
  const int swz = (lin & 7) * cpx + (lin >> 3);
  const int bx = swz % NBX, by = swz / NBX;
  const int tid = threadIdx.x, lane = tid & 63, w = tid >> 6;
  const int rowBase = by * 64, colBase = bx * 128;
  f32x4 acc[2][4] = {};
  const int srow = tid >> 3;               // 0..31
  const int sc = (tid & 7) * 8;            // shorts
  const int scs = sc ^ ((srow & 7) << 3);  // pre-swizzled source column
  const short* Ag = A  + (size_t)(rowBase + srow) * Kn + scs;
  const short* Bg = Bt + (size_t)(colBase + srow) * Kn + scs;
  const int ar = (w >> 1) * 32, bc = (w & 1) * 64;
  const int lg = lane >> 4, lg8 = lg * 8, lr = lane & 15;

  for (int kt = 0; kt < Kn; kt += 64) {
    __syncthreads();
#pragma unroll
    for (int p2 = 0; p2 < 2; ++p2)
      gload16(Ag + kt + (size_t)(p2 * 32) * Kn, &S[(p2*32 + srow)*64 + sc]);
#pragma unroll
    for (int p2 = 0; p2 < 4; ++p2)
      gload16(Bg + kt + (size_t)(p2 * 32) * Kn, &S[4096 + (p2*32 + srow)*64 + sc]);
    __syncthreads();
#pragma unroll
    for (int kk = 0; kk < 2; ++kk) {
      short8 af[2], bfr[4];
#pragma unroll
      for (int m = 0; m < 2; ++m) {
        const int row = ar + m*16 + lr;
        af[m] = *(const short8*)&S[row*64 + ((kk*32 + lg8) ^ ((row & 7) << 3))];
      }
#pragma unroll
      for (int n = 0; n < 4; ++n) {
        const int row = bc + n*16 + lr;
        bfr[n] = *(const short8*)&S[4096 + row*64 + ((kk*32 + lg8) ^ ((row & 7) << 3))];
      }
#pragma unroll
      for (int m = 0; m < 2; ++m)
#pragma unroll
        for (int n = 0; n < 4; ++n)
          acc[m][n] = mfma16(af[m], bfr[n], acc[m][n]);
    }
  }

  const int gr0 = rowBase + ar + lg * 4;
  const int gc0 = colBase + bc + lr;
  float bb[4];
#pragma unroll
  for (int n = 0; n < 4; ++n) bb[n] = bias[gc0 + n * 16];
#pragma unroll
  for (int m = 0; m < 2; ++m)
#pragma unroll
    for (int n = 0; n < 4; ++n) {
      const int gc = gc0 + n * 16;
#pragma unroll
      for (int r = 0; r < 4; ++r)
        Cf[(size_t)(gr0 + m*16 + r) * N + gc] = acc[m][n][r] + bb[n];
    }
}

// ---------------- Flash attention: swapped 32x32 (R16/R17/R19 proven) ----------------
__global__ __launch_bounds__(256) void flash32_kernel(
    const short* __restrict__ qp, const short* __restrict__ kp,
    const short* __restrict__ vt, short* __restrict__ y) {
  __shared__ char lds[32768];          // K dbuf 2x8KB | Vt dbuf 2x8KB
  char* ldsK = lds;
  char* ldsV = lds + 16384;

  const int tid = threadIdx.x, l = tid & 63, w = tid >> 6;
  const int l31 = l & 31, hi = l >> 5;

  // XCD swizzle (bijective over 1024 = 8 xcd x 8 bh x 16 qt)
  const int j0 = blockIdx.x;
  const int xcd = j0 & 7, kk0 = j0 >> 3;
  const int bh = 8 * xcd + (kk0 & 7), qt = kk0 >> 3;

  const int qrow0 = qt * 128 + w * 32;
  const short* qrow = qp + ((size_t)bh * Tn + qrow0 + l31) * Dh;
  short8 qf[4];
#pragma unroll
  for (int c = 0; c < 4; ++c)
    qf[c] = *(const short8*)&qrow[c * 16 + hi * 8];

  f32x16 o[2] = {};
  float m = -1e30f, lsum = 0.f;

  const char* kb2 = (const char*)(kp + (size_t)bh * Tn * Dh);
  const char* vb2 = (const char*)(vt + (size_t)bh * Dh * Tn);
  const int sr0 = tid >> 3;            // 0..31 (row within 32-row half)
  const int swzst = (((sr0 & 7) ^ ((sr0 >> 3) << 1)) << 4);
  const int colb = (tid & 7) << 4;
  const int swzrd = (((l31 & 7) ^ ((l31 >> 3) << 1)) << 4);

#define STAGE(jt, bsel)                                                          \
  {                                                                              \
    _Pragma("unroll")                                                            \
    for (int i = 0; i < 2; ++i) {                                                \
      const int row = i * 32 + sr0;                                              \
      const int sw = colb ^ swzst;                                               \
      gload16(kb2 + (size_t)((jt) * 64 + row) * 128 + sw,                        \
              ldsK + (bsel) * 8192 + i * 4096 + tid * 16);                       \
      gload16(vb2 + (size_t)row * (Tn * 2) + (size_t)(jt) * 128 + sw,            \
              ldsV + (bsel) * 8192 + i * 4096 + tid * 16);                       \
    }                                                                            \
  }

  STAGE(0, 0);
  __syncthreads();

  for (int j = 0; j < Tn / 64; ++j) {
    const int cur = j & 1;
    if (j + 1 < Tn / 64) STAGE(j + 1, cur ^ 1);

    const char* Kb = ldsK + cur * 8192;
    const char* Vb = ldsV + cur * 8192;

    // S^T = K * Q^T
    f32x16 p[2] = {};
    __builtin_amdgcn_s_setprio(1);
#pragma unroll
    for (int t = 0; t < 2; ++t) {
      const int row = t * 32 + l31;
#pragma unroll
      for (int c = 0; c < 4; ++c) {
        short8 a = *(const short8*)(Kb + row * 128 + ((c * 32 + hi * 16) ^ swzrd));
        p[t] = mfma32(a, qf[c], p[t]);
      }
    }
    __builtin_amdgcn_s_setprio(0);

    // lane-local online softmax (exp2 domain; scale folded in GEMM1-LN)
    float mx = fmaxf(vmax16(p[0]), vmax16(p[1]));
    mx = fmaxf(mx, __shfl_xor(mx, 32));
    if (!__all(mx - m <= 11.0f)) {
      const float mn = fmaxf(m, mx);
      const float corr = __builtin_amdgcn_exp2f(m - mn);
      lsum *= corr;
      o[0] *= corr;
      o[1] *= corr;
      m = mn;
    }
#pragma unroll
    for (int t = 0; t < 2; ++t)
#pragma unroll
      for (int e = 0; e < 16; ++e)
        p[t][e] = __builtin_amdgcn_exp2f(p[t][e] - m);
    {
      float ps = vsum16(p[0]) + vsum16(p[1]);
      lsum += ps + __shfl_xor(ps, 32);
    }

    // packed exchange: 16 perm + 8 shfl + 24 cndmask (R16 proven)
    short8 pf[4];
#pragma unroll
    for (int t = 0; t < 2; ++t)
#pragma unroll
      for (int f = 0; f < 2; ++f) {
        const int rb = 8 * f;
        const unsigned A0 = packtrunc(p[t][rb + 0], p[t][rb + 1]);
        const unsigned A1 = packtrunc(p[t][rb + 2], p[t][rb + 3]);
        const unsigned B0 = packtrunc(p[t][rb + 4], p[t][rb + 5]);
        const unsigned B1 = packtrunc(p[t][rb + 6], p[t][rb + 7]);
        const unsigned S0 = hi ? A0 : B0;
        const unsigned S1 = hi ? A1 : B1;
        const unsigned R0 = (unsigned)__shfl_xor((int)S0, 32);
        const unsigned R1 = (unsigned)__shfl_xor((int)S1, 32);
        i32x4 wv;
        wv[0] = (int)(hi ? R0 : A0);
        wv[1] = (int)(hi ? R1 : A1);
        wv[2] = (int)(hi ? B0 : R0);
        wv[3] = (int)(hi ? B1 : R1);
        pf[2*t + f] = __builtin_bit_cast(short8, wv);
      }

    // O^T += V^T * P^T
    __builtin_amdgcn_s_setprio(1);
#pragma unroll
    for (int dt = 0; dt < 2; ++dt) {
      const int row = dt * 32 + l31;
#pragma unroll
      for (int c = 0; c < 4; ++c) {
        short8 a = *(const short8*)(Vb + row * 128 + ((c * 32 + hi * 16) ^ swzrd));
        o[dt] = mfma32(a, pf[c], o[dt]);
      }
    }
    __builtin_amdgcn_s_setprio(0);

    __syncthreads();
  }
#undef STAGE

  // epilogue: lane-local normalize, direct 8B stores
  const float rl = 1.0f / lsum;
  const int b = bh >> 4, hh = bh & 15;
  const int t = qrow0 + l31;
  short* yrow = y + ((size_t)(b * Tn + t)) * En + hh * 64;
#pragma unroll
  for (int dt = 0; dt < 2; ++dt)
#pragma unroll
    for (int g = 0; g < 4; ++g) {
      short4v v4;
#pragma unroll
      for (int i = 0; i < 4; ++i) v4[i] = f2b(o[dt][g*4 + i] * rl);
      *(short4v*)&yrow[dt*32 + g*8 + hi*4] = v4;
    }
}

extern "C" void kernel_launch(void* const* d_in, const int* in_sizes, int n_in,
                              void* d_out, int out_size, void* d_ws, size_t ws_size,
                              hipStream_t stream) {
  const float* x     = (const float*)d_in[0];
  const float* Wqkv  = (const float*)d_in[1];
  const float* bqkv  = (const float*)d_in[2];
  const float* qg    = (const float*)d_in[3];
  const float* qb    = (const float*)d_in[4];
  const float* kg    = (const float*)d_in[5];
  const float* kb    = (const float*)d_in[6];
  const float* Wproj = (const float*)d_in[7];
  const float* bproj = (const float*)d_in[8];
  float* out = (float*)d_out;

  char* p = (char*)d_ws;
  short* xb     = (short*)p; p += (size_t)Mn * Kn * 2;
  short* wqkvT  = (short*)p; p += (size_t)N1 * Kn * 2;
  short* wprojT = (short*)p; p += (size_t)En * Kn * 2;
  short* qp     = (short*)p; p += (size_t)Mn * Kn * 2;
  short* kp     = (short*)p; p += (size_t)Mn * Kn * 2;
  short* vtb    = (short*)p; p += (size_t)Mn * Kn * 2;
  short* yb     = (short*)p; p += (size_t)Mn * Kn * 2;

  prep_kernel<<<8192, 256, 0, stream>>>(x, xb, Wqkv, wqkvT, Wproj, wprojT);
  gemm1_kernel<<<(N1 / 128) * (Mn / 128), 256, 0, stream>>>(
      xb, wqkvT, bqkv, qp, kp, vtb, qg, qb, kg, kb,
      N1 / 128, (N1 / 128) * (Mn / 128) / 8);
  flash32_kernel<<<1024, 256, 0, stream>>>(qp, kp, vtb, yb);
  gemm2_kernel<<<(En / 128) * (Mn / 64), 256, 0, stream>>>(
      yb, wprojT, bproj, out, En, En / 128, (En / 128) * (Mn / 64) / 8);
}